// Round 4
// baseline (88.602 us; speedup 1.0000x reference)
//
#include <hip/hip_runtime.h>

// ---------------------------------------------------------------------------
// Conv2dfft == 3x3 SAME cross-correlation conv (pad=1) + bias.
// N=32, C=128, F=128, H=W=32.  Implicit-GEMM, bf16 MFMA 16x16x32.
// Round 4: 512-thread blocks (8 waves, 2 waves/SIMD) for latency hiding at
// unchanged HBM traffic. Wave = 64f x 1 row (4x2 tiles, 32 VGPR acc).
// Weights stay global->VGPR (fragment-major, double-buffered); x stays
// LDS double-buffered per 32-channel chunk (4 barriers total).
// ---------------------------------------------------------------------------

typedef short bf16x8 __attribute__((ext_vector_type(8)));   // 8 bf16 (4 VGPR)
typedef short bf16x4 __attribute__((ext_vector_type(4)));   // 4 bf16 (2 VGPR)
typedef float f32x4  __attribute__((ext_vector_type(4)));   // MFMA 16x16 acc

__device__ __forceinline__ short f2bf(float f) {            // RNE fp32->bf16
  unsigned u = __builtin_bit_cast(unsigned, f);
  u = (u + 0x7fffu + ((u >> 16) & 1u)) >> 16;
  return (short)u;
}

// ---------------------------------------------------------------------------
// Prepass: weight (F,C,3,3) fp32 -> bf16 fragment-major:
//   bc2[chunk(4)*9+tap][fblk(8)][lane(64)][j(8)]
// A-frag element j of lane (quad*16+l15) = W[f=fblk*16+l15][c=chunk*32+quad*8+j].
// Coalesced READ (tid = linear w index), scattered 2-B writes (L2 absorbs).
// ---------------------------------------------------------------------------
__global__ __launch_bounds__(256) void conv_wprep(const float* __restrict__ w,
                                                  short* __restrict__ bc2) {
  int tid = blockIdx.x * 256 + threadIdx.x;    // [0, 147456)
  float v = w[tid];                            // coalesced
  int f   = tid / 1152;                        // w layout: f*1152 + c*9 + tap
  int rem = tid - f * 1152;
  int c   = rem / 9;
  int tap = rem - c * 9;
  int dst = ((((c >> 5) * 9 + tap) * 8 + (f >> 4)) * 512)   // [chunk*9+tap][fblk]
          + (((c >> 3) & 3) * 16 + (f & 15)) * 8            // lane = quad*16+l15
          + (c & 7);                                        // j
  bc2[dst] = f2bf(v);
}

// ---------------------------------------------------------------------------
// load_af: one weight group (chunk,p) = 3 q-taps x 4 f-tiles for this wave's
// f-half, straight from L2 as coalesced global_load_dwordx4 (base + lane*16).
// ---------------------------------------------------------------------------
__device__ __forceinline__ void load_af(bf16x8* dst, const short* __restrict__ bc2,
                                        int chunk, int p, int fsel, int lane) {
  const short* base = bc2 + (((chunk * 9 + p * 3) * 8 + fsel * 4) * 512) + lane * 8;
#pragma unroll
  for (int q = 0; q < 3; ++q)
#pragma unroll
    for (int mt = 0; mt < 4; ++mt)
      dst[q * 4 + mt] = *(const bf16x8*)(base + (q * 8 + mt) * 512);
}

// ---------------------------------------------------------------------------
// Main: 256 blocks (1/CU) x 512 threads (8 waves, 2/SIMD).
// Block = image n_img, output rows h0..h0+3, 32 cols, 128 f.
// Wave: fsel=wv&1 (f-half), s_row=wv>>1 (one output row); 4x2 acc tiles.
// ---------------------------------------------------------------------------
__global__ __launch_bounds__(512, 2) void conv_main(
    const float* __restrict__ x, const short* __restrict__ bc2,
    const float* __restrict__ bias, float* __restrict__ out) {
  // xs[buf][row(6)][col(34)][c(32 + 8 pad)] ; stride 40 shorts = 80 B:
  // bf16x8 reads 16-B aligned (ds_read_b128), conflict-free (8 accesses/bank).
  __shared__ __align__(16) short xs[2][6 * 34 * 40];      // 32640 B

  const int t    = threadIdx.x;
  const int lane = t & 63;
  const int wv   = t >> 6;
  const int n_img = blockIdx.x >> 3;
  const int h0    = (blockIdx.x & 7) << 2;

  const int l15  = lane & 15;
  const int quad = lane >> 4;
  const int fsel  = wv & 1;
  const int f_off = fsel * 64;
  const int s_row = wv >> 1;       // this wave's output row within the strip

  const int w_ = t & 31;           // staged output col (coalesced)
  const int g  = t >> 5;           // staging group [0,16)
  const float* xb = x + n_img * 128 * 1024;

  // af double-buffer: group = chunk*3+p, 12 frags (48 VGPRs) each.
  bf16x8 afA[12], afB[12];
  load_af(afA, bc2, 0, 0, fsel, lane);   // group 0 in flight ASAP

  // Zero halo cols (col 0 == w=-1, col 33 == w=32) in BOTH buffers, once.
  if (t < 192) {
    int buf = t / 96, rem = t % 96;
    int r = rem / 16, rem2 = rem % 16;
    int colsel = rem2 / 8, q4 = rem2 % 8;
    *(int2*)&xs[buf][(r * 34 + colsel * 33) * 40 + q4 * 4] = make_int2(0, 0);
  }

  f32x4 acc[4][2] = {};            // [mt(f)][nt(col-half)]
  float xv[12];

  // ---- chunk 0 x -> regs -> buf 0 : 3 (r,cq) pairs x 4 c per thread ----
#pragma unroll
  for (int i = 0; i < 3; ++i) {
    int idx = i * 16 + g;          // [0,48) = r*8 + cq
    int r = idx >> 3, cq = idx & 7;
    int hr = h0 - 1 + r;
    bool ok = (unsigned)hr < 32u;
#pragma unroll
    for (int cc = 0; cc < 4; ++cc)
      xv[i * 4 + cc] = ok ? xb[(cq * 4 + cc) * 1024 + hr * 32 + w_] : 0.f;
  }
#pragma unroll
  for (int i = 0; i < 3; ++i) {
    int idx = i * 16 + g;
    int r = idx >> 3, cq = idx & 7;
    bf16x4 v = { f2bf(xv[i*4+0]), f2bf(xv[i*4+1]), f2bf(xv[i*4+2]), f2bf(xv[i*4+3]) };
    *(bf16x4*)&xs[0][(r * 34 + w_ + 1) * 40 + cq * 4] = v;
  }
  __syncthreads();

#pragma unroll
  for (int chunk = 0; chunk < 4; ++chunk) {
    // ---- prefetch next chunk's x into regs (hides under 72 MFMAs) ----
    if (chunk < 3) {
#pragma unroll
      for (int i = 0; i < 3; ++i) {
        int idx = i * 16 + g;
        int r = idx >> 3, cq = idx & 7;
        int hr = h0 - 1 + r;
        bool ok = (unsigned)hr < 32u;
#pragma unroll
        for (int cc = 0; cc < 4; ++cc)
          xv[i * 4 + cc] =
              ok ? xb[((chunk + 1) * 32 + cq * 4 + cc) * 1024 + hr * 32 + w_] : 0.f;
      }
    }
    const short* xbuf = xs[chunk & 1];
#pragma unroll
    for (int p = 0; p < 3; ++p) {
      const int grp = chunk * 3 + p;
      const bf16x8* cur = (grp & 1) ? afB : afA;
      bf16x8*       nxt = (grp & 1) ? afA : afB;
      if (grp < 11)                 // next af group in flight across the taps
        load_af(nxt, bc2, (grp + 1) / 3, (grp + 1) % 3, fsel, lane);
#pragma unroll
      for (int q = 0; q < 3; ++q) {
        bf16x8 bfr[2];
#pragma unroll
        for (int nt = 0; nt < 2; ++nt) {
          int r   = s_row + p;
          int col = nt * 16 + l15 + q;
          bfr[nt] = *(const bf16x8*)&xbuf[(r * 34 + col) * 40 + quad * 8];
        }
#pragma unroll
        for (int mt = 0; mt < 4; ++mt)
#pragma unroll
          for (int nt = 0; nt < 2; ++nt)
            acc[mt][nt] = __builtin_amdgcn_mfma_f32_16x16x32_bf16(
                cur[q * 4 + mt], bfr[nt], acc[mt][nt], 0, 0, 0);
      }
    }
    // ---- stage prefetched x into the other buffer ----
    if (chunk < 3) {
#pragma unroll
      for (int i = 0; i < 3; ++i) {
        int idx = i * 16 + g;
        int r = idx >> 3, cq = idx & 7;
        bf16x4 v = { f2bf(xv[i*4+0]), f2bf(xv[i*4+1]), f2bf(xv[i*4+2]), f2bf(xv[i*4+3]) };
        *(bf16x4*)&xs[(chunk + 1) & 1][(r * 34 + w_ + 1) * 40 + cq * 4] = v;
      }
      __syncthreads();
    }
  }

  // ---- epilogue: C/D layout col=lane&15 (w), row=quad*4+reg (f) ----
  const int h = h0 + s_row;
#pragma unroll
  for (int nt = 0; nt < 2; ++nt) {
    int w_out = nt * 16 + l15;
#pragma unroll
    for (int mt = 0; mt < 4; ++mt) {
#pragma unroll
      for (int reg = 0; reg < 4; ++reg) {
        int f = f_off + mt * 16 + quad * 4 + reg;
        out[((n_img * 128 + f) * 32 + h) * 32 + w_out] = acc[mt][nt][reg] + bias[f];
      }
    }
  }
}

// ---------------------------------------------------------------------------
extern "C" void kernel_launch(void* const* d_in, const int* in_sizes, int n_in,
                              void* d_out, int out_size, void* d_ws, size_t ws_size,
                              hipStream_t stream) {
  const float* x    = (const float*)d_in[0];   // 32*128*32*32
  const float* w    = (const float*)d_in[1];   // 128*128*3*3
  const float* bias = (const float*)d_in[2];   // 128
  float* out = (float*)d_out;                  // 32*128*32*32
  short* bc2 = (short*)d_ws;                   // 294,912 B fragment-major weights

  conv_wprep<<<576, 256, 0, stream>>>(w, bc2);
  conv_main<<<256, 512, 0, stream>>>(x, bc2, bias, out);
}